// Round 1
// baseline (619.416 us; speedup 1.0000x reference)
//
#include <hip/hip_runtime.h>
#include <math.h>

#define N_ROWS 131072
#define DIM 64
#define K_CODES 1024

// ws layout:
//   [0,    8)     double loss_sum
//   [256,  4352)  u32 counts[1024]
//   [8192, 12288) float esq[1024]

__global__ void vq_esq(const float* __restrict__ cb, float* __restrict__ esq) {
    int k = blockIdx.x * blockDim.x + threadIdx.x;  // 1024 threads total
    if (k >= K_CODES) return;
    const float4* c = reinterpret_cast<const float4*>(cb + (size_t)k * DIM);
    float s = 0.f;
#pragma unroll
    for (int i = 0; i < DIM / 4; ++i) {
        float4 v = c[i];
        s = fmaf(v.x, v.x, s);
        s = fmaf(v.y, v.y, s);
        s = fmaf(v.z, v.z, s);
        s = fmaf(v.w, v.w, s);
    }
    esq[k] = s;
}

__global__ __launch_bounds__(256) void vq_main(
    const float* __restrict__ x, const float* __restrict__ cb,
    const float* __restrict__ esq, float* __restrict__ outq,
    double* __restrict__ loss_sum, unsigned int* __restrict__ counts) {
    const int row = blockIdx.x * 256 + threadIdx.x;

    // Load this thread's row into registers (64 VGPRs).
    float xr[DIM];
    const float4* xp = reinterpret_cast<const float4*>(x + (size_t)row * DIM);
#pragma unroll
    for (int i = 0; i < DIM / 4; ++i) {
        float4 v = xp[i];
        xr[4 * i + 0] = v.x;
        xr[4 * i + 1] = v.y;
        xr[4 * i + 2] = v.z;
        xr[4 * i + 3] = v.w;
    }

    float best = 3.4e38f;
    int bidx = 0;
#pragma unroll 1
    for (int k = 0; k < K_CODES; k += 4) {
        const float* c0 = cb + (size_t)k * DIM;
        float d0 = 0.f, d1 = 0.f, d2 = 0.f, d3 = 0.f;
#pragma unroll
        for (int d = 0; d < DIM; ++d) {
            // c0[...] has a wave-uniform address -> expect s_load + v_fmac(s,v)
            d0 = fmaf(c0[0 * DIM + d], xr[d], d0);
            d1 = fmaf(c0[1 * DIM + d], xr[d], d1);
            d2 = fmaf(c0[2 * DIM + d], xr[d], d2);
            d3 = fmaf(c0[3 * DIM + d], xr[d], d3);
        }
        // dist' = e_sq - 2*dot  (x_sq dropped; argmin-equivalent)
        float t0 = fmaf(-2.f, d0, esq[k + 0]);
        float t1 = fmaf(-2.f, d1, esq[k + 1]);
        float t2 = fmaf(-2.f, d2, esq[k + 2]);
        float t3 = fmaf(-2.f, d3, esq[k + 3]);
        // strict < in ascending k == jnp.argmin first-min tie-break
        if (t0 < best) { best = t0; bidx = k + 0; }
        if (t1 < best) { best = t1; bidx = k + 1; }
        if (t2 < best) { best = t2; bidx = k + 2; }
        if (t3 < best) { best = t3; bidx = k + 3; }
    }

    // Epilogue: gather chosen code, write quantized_st, accumulate loss.
    const float4* q = reinterpret_cast<const float4*>(cb + (size_t)bidx * DIM);
    float4* o = reinterpret_cast<float4*>(outq + (size_t)row * DIM);
    float ls = 0.f;
#pragma unroll
    for (int i = 0; i < DIM / 4; ++i) {
        float4 qv = q[i];
        o[i] = qv;
        float e0 = qv.x - xr[4 * i + 0];
        float e1 = qv.y - xr[4 * i + 1];
        float e2 = qv.z - xr[4 * i + 2];
        float e3 = qv.w - xr[4 * i + 3];
        ls = fmaf(e0, e0, ls);
        ls = fmaf(e1, e1, ls);
        ls = fmaf(e2, e2, ls);
        ls = fmaf(e3, e3, ls);
    }
    atomicAdd(&counts[bidx], 1u);

    __shared__ float red[256];
    red[threadIdx.x] = ls;
    __syncthreads();
#pragma unroll
    for (int s = 128; s > 0; s >>= 1) {
        if (threadIdx.x < s) red[threadIdx.x] += red[threadIdx.x + s];
        __syncthreads();
    }
    if (threadIdx.x == 0) atomicAdd(loss_sum, (double)red[0]);
}

__global__ void vq_finalize(const unsigned int* __restrict__ counts,
                            const double* __restrict__ loss_sum,
                            float* __restrict__ out) {
    const int t = threadIdx.x;  // 1024 threads, 1 block
    float p = (float)counts[t] * (1.0f / (float)N_ROWS);
    float term = p * logf(p + 1e-10f);

    __shared__ float red[1024];
    red[t] = term;
    __syncthreads();
#pragma unroll
    for (int s = 512; s > 0; s >>= 1) {
        if (t < s) red[t] += red[t + s];
        __syncthreads();
    }
    if (t == 0) {
        float H = -red[0];
        double mean = *loss_sum / (double)((size_t)N_ROWS * DIM);
        out[0] = (float)(1.25 * mean);                   // q_loss + 0.25*e_loss
        out[1 + (size_t)N_ROWS * DIM] = expf(H);         // perplexity
    }
}

extern "C" void kernel_launch(void* const* d_in, const int* in_sizes, int n_in,
                              void* d_out, int out_size, void* d_ws, size_t ws_size,
                              hipStream_t stream) {
    const float* x  = (const float*)d_in[0];   // [131072, 64] f32
    const float* cb = (const float*)d_in[1];   // [1024, 64] f32
    float* out = (float*)d_out;                // [1 + N*D + 1] f32
    char* ws = (char*)d_ws;

    double* loss = (double*)ws;
    unsigned int* counts = (unsigned int*)(ws + 256);
    float* esq = (float*)(ws + 8192);

    hipMemsetAsync(ws, 0, 4352, stream);  // loss_sum + counts
    vq_esq<<<4, 256, 0, stream>>>(cb, esq);
    vq_main<<<N_ROWS / 256, 256, 0, stream>>>(x, cb, esq, out + 1, loss, counts);
    vq_finalize<<<1, 1024, 0, stream>>>(counts, loss, out);
}

// Round 2
// 177.263 us; speedup vs baseline: 3.4943x; 3.4943x over previous
//
#include <hip/hip_runtime.h>
#include <math.h>

#define N_ROWS 131072
#define DIM 64
#define K_CODES 1024
#define CHUNK 256       // codes staged per LDS chunk
#define BLK_ROWS 256    // rows per workgroup
#define THREADS 256

typedef __attribute__((ext_vector_type(8))) short bf16x8;
typedef __attribute__((ext_vector_type(4))) float f32x4;

__device__ inline unsigned short bf16_rn(float f) {
    unsigned int u = __builtin_bit_cast(unsigned int, f);
    u += 0x7fffu + ((u >> 16) & 1u);   // round-to-nearest-even
    return (unsigned short)(u >> 16);
}
__device__ inline float bf16_to_f(unsigned short h) {
    unsigned int u = ((unsigned int)h) << 16;
    return __builtin_bit_cast(float, u);
}

// ws layout:
//   [0,8) double loss_sum | [256,4352) u32 counts[1024] | [8192,12288) f32 esq[1024]
//   [16384, +128K) bf16 cb_hi[1024][64] | [147456, +128K) bf16 cb_lo[1024][64]

__global__ void vq_prep(const float* __restrict__ cb, float* __restrict__ esq,
                        uint4* __restrict__ cbhi, uint4* __restrict__ cblo) {
    const int k = blockIdx.x * blockDim.x + threadIdx.x;   // one code per thread
    if (k >= K_CODES) return;
    const float4* c = (const float4*)(cb + (size_t)k * DIM);
    float s = 0.f;
#pragma unroll
    for (int i = 0; i < 8; ++i) {                          // 8 floats per iter
        float4 a = c[2 * i], b = c[2 * i + 1];
        float f[8] = {a.x, a.y, a.z, a.w, b.x, b.y, b.z, b.w};
        unsigned int hw[4], lw[4];
#pragma unroll
        for (int p = 0; p < 4; ++p) {
            float f0 = f[2 * p], f1 = f[2 * p + 1];
            s = fmaf(f0, f0, s);
            s = fmaf(f1, f1, s);
            unsigned short h0 = bf16_rn(f0), h1 = bf16_rn(f1);
            unsigned short l0 = bf16_rn(f0 - bf16_to_f(h0));
            unsigned short l1 = bf16_rn(f1 - bf16_to_f(h1));
            hw[p] = (unsigned int)h0 | ((unsigned int)h1 << 16);
            lw[p] = (unsigned int)l0 | ((unsigned int)l1 << 16);
        }
        cbhi[(size_t)k * 8 + i] = make_uint4(hw[0], hw[1], hw[2], hw[3]);
        cblo[(size_t)k * 8 + i] = make_uint4(lw[0], lw[1], lw[2], lw[3]);
    }
    esq[k] = s;
}

__global__ __launch_bounds__(THREADS, 2) void vq_main(
    const float* __restrict__ x, const float* __restrict__ cb,
    const float* __restrict__ esq_g,
    const uint4* __restrict__ cbhi, const uint4* __restrict__ cblo,
    float* __restrict__ outq,
    double* __restrict__ loss_sum, unsigned int* __restrict__ counts)
{
    __shared__ __align__(16) char s_hi[CHUNK * 128];   // 32 KB, XOR-swizzled slots
    __shared__ __align__(16) char s_lo[CHUNK * 128];   // 32 KB
    __shared__ __align__(16) float s_esq[K_CODES];     // 4 KB
    __shared__ float s_red[THREADS];

    const int t  = threadIdx.x;
    const int w  = t >> 6;        // wave 0..3
    const int l  = t & 63;        // lane
    const int g  = l >> 4;        // k-group 0..3
    const int li = l & 15;

    const int R0 = blockIdx.x * BLK_ROWS;

    // ---- x rows -> split-bf16 B fragments, kept in registers all kernel ----
    bf16x8 xh[4][2], xl[4][2];
#pragma unroll
    for (int rg = 0; rg < 4; ++rg) {
        const int row = R0 + w * 64 + rg * 16 + li;
        const float* xp = x + (size_t)row * DIM;
#pragma unroll
        for (int h = 0; h < 2; ++h) {
            const float4 p0 = *(const float4*)(xp + h * 32 + g * 8);
            const float4 p1 = *(const float4*)(xp + h * 32 + g * 8 + 4);
            float f[8] = {p0.x, p0.y, p0.z, p0.w, p1.x, p1.y, p1.z, p1.w};
            bf16x8 hv, lv;
#pragma unroll
            for (int j = 0; j < 8; ++j) {
                unsigned short hb = bf16_rn(f[j]);
                unsigned short lb = bf16_rn(f[j] - bf16_to_f(hb));
                hv[j] = (short)hb;
                lv[j] = (short)lb;
            }
            xh[rg][h] = hv;
            xl[rg][h] = lv;
        }
    }

    // stage esq once (256 threads x 16B = 4KB); chunk-0 barrier covers it
    ((float4*)s_esq)[t] = ((const float4*)esq_g)[t];

    float best[4];
    int   bidx[4];
#pragma unroll
    for (int rg = 0; rg < 4; ++rg) { best[rg] = 3.4e38f; bidx[rg] = 0; }

    for (int chunk = 0; chunk < K_CODES / CHUNK; ++chunk) {
        if (chunk) __syncthreads();        // previous compute done before restage
        // stage 256 codes of hi+lo, slot-swizzled: lds[c][s^(c&7)] = g[c][s]
#pragma unroll
        for (int i = 0; i < 8; ++i) {
            const int n = i * THREADS + t;           // 16B-chunk id 0..2047
            const int c = n >> 3, s = n & 7;
            const int dst = c * 128 + (((s ^ (c & 7))) << 4);
            *(uint4*)(s_hi + dst) = cbhi[(size_t)(chunk * CHUNK + c) * 8 + s];
            *(uint4*)(s_lo + dst) = cblo[(size_t)(chunk * CHUNK + c) * 8 + s];
        }
        __syncthreads();

#pragma unroll 1
        for (int tb = 0; tb < CHUNK / 16; ++tb) {
            const int c  = tb * 16 + li;             // A-row (code) this lane serves
            const int sw = c & 7;
            const int b0 = c * 128 + (((0 + g) ^ sw) << 4);   // k 0..31 slot g
            const int b1 = c * 128 + (((4 + g) ^ sw) << 4);   // k 32..63 slot 4+g
            const bf16x8 ah0 = *(const bf16x8*)(s_hi + b0);
            const bf16x8 ah1 = *(const bf16x8*)(s_hi + b1);
            const bf16x8 al0 = *(const bf16x8*)(s_lo + b0);
            const bf16x8 al1 = *(const bf16x8*)(s_lo + b1);
            const int cb0 = chunk * CHUNK + tb * 16 + g * 4;  // this lane's 4 codes
            const float4 e4 = *(const float4*)(s_esq + cb0);
#pragma unroll
            for (int rg = 0; rg < 4; ++rg) {
                f32x4 acc = {0.f, 0.f, 0.f, 0.f};
                acc = __builtin_amdgcn_mfma_f32_16x16x32_bf16(ah0, xh[rg][0], acc, 0, 0, 0);
                acc = __builtin_amdgcn_mfma_f32_16x16x32_bf16(ah1, xh[rg][1], acc, 0, 0, 0);
                acc = __builtin_amdgcn_mfma_f32_16x16x32_bf16(ah0, xl[rg][0], acc, 0, 0, 0);
                acc = __builtin_amdgcn_mfma_f32_16x16x32_bf16(ah1, xl[rg][1], acc, 0, 0, 0);
                acc = __builtin_amdgcn_mfma_f32_16x16x32_bf16(al0, xh[rg][0], acc, 0, 0, 0);
                acc = __builtin_amdgcn_mfma_f32_16x16x32_bf16(al1, xh[rg][1], acc, 0, 0, 0);
                // dist' = esq - 2*dot; ascending-code strict '<' = first-min tie-break
                float t0 = fmaf(-2.f, acc[0], e4.x);
                float t1 = fmaf(-2.f, acc[1], e4.y);
                float t2 = fmaf(-2.f, acc[2], e4.z);
                float t3 = fmaf(-2.f, acc[3], e4.w);
                if (t0 < best[rg]) { best[rg] = t0; bidx[rg] = cb0 + 0; }
                if (t1 < best[rg]) { best[rg] = t1; bidx[rg] = cb0 + 1; }
                if (t2 < best[rg]) { best[rg] = t2; bidx[rg] = cb0 + 2; }
                if (t3 < best[rg]) { best[rg] = t3; bidx[rg] = cb0 + 3; }
            }
        }
    }

    // ---- merge argmin across the 4 k-groups (codes interleaved mod 16) ----
#pragma unroll
    for (int rg = 0; rg < 4; ++rg) {
#pragma unroll
        for (int d = 16; d <= 32; d <<= 1) {
            float ob = __shfl_xor(best[rg], d, 64);
            int   oi = __shfl_xor(bidx[rg], d, 64);
            if (ob < best[rg] || (ob == best[rg] && oi < bidx[rg])) {
                best[rg] = ob;
                bidx[rg] = oi;
            }
        }
    }

    // ---- epilogue: gather code, write quantized, loss partial, histogram ----
    float ls = 0.f;
#pragma unroll
    for (int rg = 0; rg < 4; ++rg) {
        const int row = R0 + w * 64 + rg * 16 + li;
        const int idx = bidx[rg];
        if (g == 0) atomicAdd(&counts[idx], 1u);
        const float4* qp = (const float4*)(cb + (size_t)idx * DIM);
        float* op = outq + (size_t)row * DIM;
#pragma unroll
        for (int h = 0; h < 2; ++h) {
            float4 q0 = qp[h * 8 + g * 2];
            float4 q1 = qp[h * 8 + g * 2 + 1];
            *(float4*)(op + h * 32 + g * 8)     = q0;
            *(float4*)(op + h * 32 + g * 8 + 4) = q1;
            float qq[8] = {q0.x, q0.y, q0.z, q0.w, q1.x, q1.y, q1.z, q1.w};
#pragma unroll
            for (int j = 0; j < 8; ++j) {
                float xv = bf16_to_f((unsigned short)xh[rg][h][j])
                         + bf16_to_f((unsigned short)xl[rg][h][j]);
                float e = qq[j] - xv;
                ls = fmaf(e, e, ls);
            }
        }
    }

    s_red[t] = ls;
    __syncthreads();
#pragma unroll
    for (int s = THREADS / 2; s > 0; s >>= 1) {
        if (t < s) s_red[t] += s_red[t + s];
        __syncthreads();
    }
    if (t == 0) atomicAdd(loss_sum, (double)s_red[0]);
}

__global__ void vq_finalize(const unsigned int* __restrict__ counts,
                            const double* __restrict__ loss_sum,
                            float* __restrict__ out) {
    const int t = threadIdx.x;  // 1024 threads, 1 block
    float p = (float)counts[t] * (1.0f / (float)N_ROWS);
    float term = p * logf(p + 1e-10f);

    __shared__ float red[1024];
    red[t] = term;
    __syncthreads();
#pragma unroll
    for (int s = 512; s > 0; s >>= 1) {
        if (t < s) red[t] += red[t + s];
        __syncthreads();
    }
    if (t == 0) {
        float H = -red[0];
        double mean = *loss_sum / (double)((size_t)N_ROWS * DIM);
        out[0] = (float)(1.25 * mean);                 // q_loss + 0.25*e_loss
        out[1 + (size_t)N_ROWS * DIM] = expf(H);       // perplexity
    }
}

extern "C" void kernel_launch(void* const* d_in, const int* in_sizes, int n_in,
                              void* d_out, int out_size, void* d_ws, size_t ws_size,
                              hipStream_t stream) {
    const float* x  = (const float*)d_in[0];   // [131072, 64] f32
    const float* cb = (const float*)d_in[1];   // [1024, 64] f32
    float* out = (float*)d_out;                // [1 + N*D + 1] f32
    char* ws = (char*)d_ws;

    double*       loss   = (double*)ws;
    unsigned int* counts = (unsigned int*)(ws + 256);
    float*        esq    = (float*)(ws + 8192);
    uint4*        cbhi   = (uint4*)(ws + 16384);
    uint4*        cblo   = (uint4*)(ws + 16384 + 131072);

    hipMemsetAsync(ws, 0, 4352, stream);  // loss_sum + counts
    vq_prep<<<4, 256, 0, stream>>>(cb, esq, cbhi, cblo);
    vq_main<<<N_ROWS / BLK_ROWS, THREADS, 0, stream>>>(x, cb, esq, cbhi, cblo,
                                                       out + 1, loss, counts);
    vq_finalize<<<1, 1024, 0, stream>>>(counts, loss, out);
}